// Round 1
// baseline (3326.342 us; speedup 1.0000x reference)
//
#include <hip/hip_runtime.h>

// ---------------------------------------------------------------------------
// HeteroGNN: u = x_user@W_user + b_user
//            out = relu( mean_img@Wl_img + bl_img + u@Wr_img
//                      + mean_txt@Wl_txt + bl_txt + u@Wr_txt )
// Folded: u@(Wr_img+Wr_txt), bias (bl_img+bl_txt).
// ---------------------------------------------------------------------------

// ---- combine Wr matrices and biases (tiny) ----
__global__ void k_combine(const float* __restrict__ Wr_img, const float* __restrict__ Wr_txt,
                          const float* __restrict__ bl_img, const float* __restrict__ bl_txt,
                          float* __restrict__ Wr_sum, float* __restrict__ bsum) {
    int i = blockIdx.x * blockDim.x + threadIdx.x;
    if (i < 128 * 128) Wr_sum[i] = Wr_img[i] + Wr_txt[i];
    if (i < 128) bsum[i] = bl_img[i] + bl_txt[i];
}

// ---- u = X[N,256] @ W[256,128] + b ----
// 256 threads, 8 rows/block. c = tid&127, rg = tid>>7; rows rg, rg+2, rg+4, rg+6.
__global__ __launch_bounds__(256) void k_user_gemm(
        const float* __restrict__ X, const float* __restrict__ W,
        const float* __restrict__ b, float* __restrict__ Y, int nrows) {
    __shared__ float xs[8][257];
    const int tid = threadIdx.x;
    const int base = blockIdx.x * 8;

    // stage 8x256 x-tile (float4 loads)
    for (int f = tid; f < 512; f += 256) {
        int r = f >> 6, kq = (f & 63) * 4;
        int row = base + r;
        float4 v = make_float4(0.f, 0.f, 0.f, 0.f);
        if (row < nrows) v = *reinterpret_cast<const float4*>(X + (size_t)row * 256 + kq);
        xs[r][kq + 0] = v.x; xs[r][kq + 1] = v.y;
        xs[r][kq + 2] = v.z; xs[r][kq + 3] = v.w;
    }
    __syncthreads();

    const int c  = tid & 127;
    const int rg = tid >> 7;
    float acc0 = 0.f, acc1 = 0.f, acc2 = 0.f, acc3 = 0.f;
    #pragma unroll 4
    for (int k = 0; k < 256; ++k) {
        float wv = W[k * 128 + c];            // coalesced row of W
        acc0 += xs[rg + 0][k] * wv;           // LDS broadcasts (wave-uniform addr)
        acc1 += xs[rg + 2][k] * wv;
        acc2 += xs[rg + 4][k] * wv;
        acc3 += xs[rg + 6][k] * wv;
    }
    float bv = b[c];
    int r0 = base + rg;
    if (r0 + 0 < nrows) Y[(size_t)(r0 + 0) * 128 + c] = acc0 + bv;
    if (r0 + 2 < nrows) Y[(size_t)(r0 + 2) * 128 + c] = acc1 + bv;
    if (r0 + 4 < nrows) Y[(size_t)(r0 + 4) * 128 + c] = acc2 + bv;
    if (r0 + 6 < nrows) Y[(size_t)(r0 + 6) * 128 + c] = acc3 + bv;
}

// ---- edge aggregation: agg[dst] += x_src[src]; cnt[dst] += 1 ----
// 32 lanes per edge, float4 per lane.
__global__ __launch_bounds__(256) void k_edge_agg(
        const float* __restrict__ xsrc, const int* __restrict__ edge,
        float* __restrict__ agg, float* __restrict__ cnt, int E) {
    int t = blockIdx.x * blockDim.x + threadIdx.x;
    int e = t >> 5;
    int lane = t & 31;
    if (e >= E) return;
    int src = edge[e];
    int dst = edge[E + e];
    float4 v = *reinterpret_cast<const float4*>(xsrc + (size_t)src * 128 + lane * 4);
    float* a = agg + (size_t)dst * 128 + lane * 4;
    atomicAdd(a + 0, v.x);
    atomicAdd(a + 1, v.y);
    atomicAdd(a + 2, v.z);
    atomicAdd(a + 3, v.w);
    if (lane == 0) atomicAdd(cnt + dst, 1.0f);
}

// ---- fused epilogue: means + 3 GEMMs (K=128) + bias + relu ----
__global__ __launch_bounds__(256) void k_final(
        const float* __restrict__ agg_i, const float* __restrict__ cnt_i,
        const float* __restrict__ agg_t, const float* __restrict__ cnt_t,
        const float* __restrict__ U,
        const float* __restrict__ Wl_i, const float* __restrict__ Wl_t,
        const float* __restrict__ Wr_s, const float* __restrict__ bsum,
        float* __restrict__ out, int nrows) {
    __shared__ float mi[8][129], mt[8][129], us[8][129];
    const int tid = threadIdx.x;
    const int base = blockIdx.x * 8;

    // stage means + u rows: one float4 slot per thread (8 rows * 128 / 4 = 256)
    {
        int r = tid >> 5, c0 = (tid & 31) * 4;
        int row = base + r;
        float4 a = make_float4(0.f, 0.f, 0.f, 0.f);
        float4 bt = a, u4 = a;
        float ri = 1.f, rt = 1.f;
        if (row < nrows) {
            ri = 1.0f / fmaxf(cnt_i[row], 1.0f);
            rt = 1.0f / fmaxf(cnt_t[row], 1.0f);
            a  = *reinterpret_cast<const float4*>(agg_i + (size_t)row * 128 + c0);
            bt = *reinterpret_cast<const float4*>(agg_t + (size_t)row * 128 + c0);
            u4 = *reinterpret_cast<const float4*>(U     + (size_t)row * 128 + c0);
        }
        mi[r][c0 + 0] = a.x * ri;  mi[r][c0 + 1] = a.y * ri;
        mi[r][c0 + 2] = a.z * ri;  mi[r][c0 + 3] = a.w * ri;
        mt[r][c0 + 0] = bt.x * rt; mt[r][c0 + 1] = bt.y * rt;
        mt[r][c0 + 2] = bt.z * rt; mt[r][c0 + 3] = bt.w * rt;
        us[r][c0 + 0] = u4.x;      us[r][c0 + 1] = u4.y;
        us[r][c0 + 2] = u4.z;      us[r][c0 + 3] = u4.w;
    }
    __syncthreads();

    const int c  = tid & 127;
    const int rg = tid >> 7;
    float acc0 = 0.f, acc1 = 0.f, acc2 = 0.f, acc3 = 0.f;
    #pragma unroll 2
    for (int k = 0; k < 128; ++k) {
        float w1 = Wl_i[k * 128 + c];
        float w2 = Wl_t[k * 128 + c];
        float w3 = Wr_s[k * 128 + c];
        acc0 += mi[rg + 0][k] * w1 + mt[rg + 0][k] * w2 + us[rg + 0][k] * w3;
        acc1 += mi[rg + 2][k] * w1 + mt[rg + 2][k] * w2 + us[rg + 2][k] * w3;
        acc2 += mi[rg + 4][k] * w1 + mt[rg + 4][k] * w2 + us[rg + 4][k] * w3;
        acc3 += mi[rg + 6][k] * w1 + mt[rg + 6][k] * w2 + us[rg + 6][k] * w3;
    }
    float bv = bsum[c];
    int r0 = base + rg;
    if (r0 + 0 < nrows) out[(size_t)(r0 + 0) * 128 + c] = fmaxf(acc0 + bv, 0.f);
    if (r0 + 2 < nrows) out[(size_t)(r0 + 2) * 128 + c] = fmaxf(acc1 + bv, 0.f);
    if (r0 + 4 < nrows) out[(size_t)(r0 + 4) * 128 + c] = fmaxf(acc2 + bv, 0.f);
    if (r0 + 6 < nrows) out[(size_t)(r0 + 6) * 128 + c] = fmaxf(acc3 + bv, 0.f);
}

extern "C" void kernel_launch(void* const* d_in, const int* in_sizes, int n_in,
                              void* d_out, int out_size, void* d_ws, size_t ws_size,
                              hipStream_t stream) {
    const float* x_user  = (const float*)d_in[0];
    const float* x_image = (const float*)d_in[1];
    const float* x_text  = (const float*)d_in[2];
    const int*   edge_i  = (const int*)d_in[3];
    const int*   edge_t  = (const int*)d_in[4];
    const float* W_user  = (const float*)d_in[5];
    const float* b_user  = (const float*)d_in[6];
    const float* Wl_img  = (const float*)d_in[7];
    const float* bl_img  = (const float*)d_in[8];
    const float* Wr_img  = (const float*)d_in[9];
    const float* Wl_txt  = (const float*)d_in[10];
    const float* bl_txt  = (const float*)d_in[11];
    const float* Wr_txt  = (const float*)d_in[12];

    const int N = in_sizes[0] / 256;   // 100000 users (also N_IMG/N_TXT rows)
    const int E = in_sizes[3] / 2;     // 800000 edges per relation

    float* ws    = (float*)d_ws;
    float* u     = ws;                          // N*128
    float* agg_i = u     + (size_t)N * 128;     // N*128
    float* agg_t = agg_i + (size_t)N * 128;     // N*128
    float* cnt_i = agg_t + (size_t)N * 128;     // N
    float* cnt_t = cnt_i + N;                   // N
    float* Wr_s  = cnt_t + N;                   // 128*128
    float* bsum  = Wr_s  + 128 * 128;           // 128

    // zero agg_i, agg_t, cnt_i, cnt_t (contiguous)
    hipMemsetAsync(agg_i, 0, ((size_t)2 * N * 128 + 2 * N) * sizeof(float), stream);

    k_combine<<<(128 * 128 + 255) / 256, 256, 0, stream>>>(
        Wr_img, Wr_txt, bl_img, bl_txt, Wr_s, bsum);

    k_user_gemm<<<(N + 7) / 8, 256, 0, stream>>>(x_user, W_user, b_user, u, N);

    {
        long long tot = (long long)E * 32;
        int grid = (int)((tot + 255) / 256);
        k_edge_agg<<<grid, 256, 0, stream>>>(x_image, edge_i, agg_i, cnt_i, E);
        k_edge_agg<<<grid, 256, 0, stream>>>(x_text,  edge_t, agg_t, cnt_t, E);
    }

    k_final<<<(N + 7) / 8, 256, 0, stream>>>(
        agg_i, cnt_i, agg_t, cnt_t, u, Wl_img, Wl_txt, Wr_s, bsum,
        (float*)d_out, N);
}

// Round 2
// 831.918 us; speedup vs baseline: 3.9984x; 3.9984x over previous
//
#include <hip/hip_runtime.h>

// ---------------------------------------------------------------------------
// HeteroGNN: u = x_user@W_user + b_user
//            out = relu( mean_img@Wl_img + bl_img + u@Wr_img
//                      + mean_txt@Wl_txt + bl_txt + u@Wr_txt )
// Folded: u@(Wr_img+Wr_txt), bias (bl_img+bl_txt).
// Aggregation: on-the-fly CSR (hist/scan/scatter) + atomic-free gather-mean.
// ---------------------------------------------------------------------------

#define SCAN_CHUNK 1024

// ---- combine Wr matrices and biases (tiny) ----
__global__ void k_combine(const float* __restrict__ Wr_img, const float* __restrict__ Wr_txt,
                          const float* __restrict__ bl_img, const float* __restrict__ bl_txt,
                          float* __restrict__ Wr_sum, float* __restrict__ bsum) {
    int i = blockIdx.x * blockDim.x + threadIdx.x;
    if (i < 128 * 128) Wr_sum[i] = Wr_img[i] + Wr_txt[i];
    if (i < 128) bsum[i] = bl_img[i] + bl_txt[i];
}

// ---- u = X[N,256] @ W[256,128] + b ----
__global__ __launch_bounds__(256) void k_user_gemm(
        const float* __restrict__ X, const float* __restrict__ W,
        const float* __restrict__ b, float* __restrict__ Y, int nrows) {
    __shared__ float xs[8][257];
    const int tid = threadIdx.x;
    const int base = blockIdx.x * 8;

    for (int f = tid; f < 512; f += 256) {
        int r = f >> 6, kq = (f & 63) * 4;
        int row = base + r;
        float4 v = make_float4(0.f, 0.f, 0.f, 0.f);
        if (row < nrows) v = *reinterpret_cast<const float4*>(X + (size_t)row * 256 + kq);
        xs[r][kq + 0] = v.x; xs[r][kq + 1] = v.y;
        xs[r][kq + 2] = v.z; xs[r][kq + 3] = v.w;
    }
    __syncthreads();

    const int c  = tid & 127;
    const int rg = tid >> 7;
    float acc0 = 0.f, acc1 = 0.f, acc2 = 0.f, acc3 = 0.f;
    #pragma unroll 4
    for (int k = 0; k < 256; ++k) {
        float wv = W[k * 128 + c];
        acc0 += xs[rg + 0][k] * wv;
        acc1 += xs[rg + 2][k] * wv;
        acc2 += xs[rg + 4][k] * wv;
        acc3 += xs[rg + 6][k] * wv;
    }
    float bv = b[c];
    int r0 = base + rg;
    if (r0 + 0 < nrows) Y[(size_t)(r0 + 0) * 128 + c] = acc0 + bv;
    if (r0 + 2 < nrows) Y[(size_t)(r0 + 2) * 128 + c] = acc1 + bv;
    if (r0 + 4 < nrows) Y[(size_t)(r0 + 4) * 128 + c] = acc2 + bv;
    if (r0 + 6 < nrows) Y[(size_t)(r0 + 6) * 128 + c] = acc3 + bv;
}

// ---- CSR build: histogram of dst ----
__global__ __launch_bounds__(256) void k_hist(const int* __restrict__ edge,
                                              int* __restrict__ deg, int E) {
    int e = blockIdx.x * 256 + threadIdx.x;
    if (e < E) atomicAdd(&deg[edge[E + e]], 1);
}

// ---- scan pass 1: per-chunk sums ----
__global__ __launch_bounds__(256) void k_scan1(const int* __restrict__ deg,
                                               int* __restrict__ bsum, int N) {
    __shared__ int sh[256];
    int base = blockIdx.x * SCAN_CHUNK;
    int t = threadIdx.x;
    int s = 0;
    #pragma unroll
    for (int j = 0; j < 4; ++j) {
        int idx = base + j * 256 + t;
        if (idx < N) s += deg[idx];
    }
    sh[t] = s; __syncthreads();
    for (int off = 128; off > 0; off >>= 1) {
        if (t < off) sh[t] += sh[t + off];
        __syncthreads();
    }
    if (t == 0) bsum[blockIdx.x] = sh[0];
}

// ---- scan pass 2: serial exclusive scan of chunk sums (nb ~ 98) ----
__global__ void k_scan2(int* __restrict__ bsum, int nb,
                        int* __restrict__ rowptr, int N, int E) {
    if (threadIdx.x == 0 && blockIdx.x == 0) {
        int run = 0;
        for (int b = 0; b < nb; ++b) { int v = bsum[b]; bsum[b] = run; run += v; }
        rowptr[N] = E;
    }
}

// ---- scan pass 3: intra-chunk exclusive scan; write rowptr + cursor(in deg) ----
__global__ __launch_bounds__(256) void k_scan3(int* __restrict__ deg /* in: counts, out: cursor */,
                                               int* __restrict__ rowptr,
                                               const int* __restrict__ bsum, int N) {
    __shared__ int sh[256];
    int base = blockIdx.x * SCAN_CHUNK;
    int t = threadIdx.x;
    int v[4]; int s = 0;
    #pragma unroll
    for (int j = 0; j < 4; ++j) {
        int idx = base + 4 * t + j;
        v[j] = (idx < N) ? deg[idx] : 0;
        s += v[j];
    }
    sh[t] = s; __syncthreads();
    // Hillis-Steele inclusive scan over 256 thread sums
    for (int off = 1; off < 256; off <<= 1) {
        int add = (t >= off) ? sh[t - off] : 0;
        __syncthreads();
        sh[t] += add;
        __syncthreads();
    }
    int run = sh[t] - s + bsum[blockIdx.x];   // exclusive prefix for this thread
    #pragma unroll
    for (int j = 0; j < 4; ++j) {
        int idx = base + 4 * t + j;
        if (idx < N) { rowptr[idx] = run; deg[idx] = run; run += v[j]; }
    }
}

// ---- scatter: place src indices into CSR buckets ----
__global__ __launch_bounds__(256) void k_scatter(const int* __restrict__ edge,
                                                 int* __restrict__ cursor,
                                                 int* __restrict__ col, int E) {
    int e = blockIdx.x * 256 + threadIdx.x;
    if (e < E) {
        int d = edge[E + e];
        int p = atomicAdd(&cursor[d], 1);
        col[p] = edge[e];
    }
}

// ---- gather-mean: 32 lanes per destination node, atomic-free ----
__global__ __launch_bounds__(256) void k_gather_mean(
        const float* __restrict__ xsrc, const int* __restrict__ rowptr,
        const int* __restrict__ col, float* __restrict__ mean, int N) {
    int t = blockIdx.x * 256 + threadIdx.x;
    int node = t >> 5, lane = t & 31;
    if (node >= N) return;
    int beg = rowptr[node], end = rowptr[node + 1];
    float ax = 0.f, ay = 0.f, az = 0.f, aw = 0.f;
    for (int j = beg; j < end; ++j) {
        int s = col[j];
        float4 v = *reinterpret_cast<const float4*>(xsrc + (size_t)s * 128 + lane * 4);
        ax += v.x; ay += v.y; az += v.z; aw += v.w;
    }
    float r = (end > beg) ? 1.0f / (float)(end - beg) : 0.0f;
    float4 o = make_float4(ax * r, ay * r, az * r, aw * r);
    *reinterpret_cast<float4*>(mean + (size_t)node * 128 + lane * 4) = o;
}

// ---- fused epilogue: 3 GEMMs (K=128) + bias + relu ----
__global__ __launch_bounds__(256) void k_final(
        const float* __restrict__ mean_i, const float* __restrict__ mean_t,
        const float* __restrict__ U,
        const float* __restrict__ Wl_i, const float* __restrict__ Wl_t,
        const float* __restrict__ Wr_s, const float* __restrict__ bsum,
        float* __restrict__ out, int nrows) {
    __shared__ float mi[8][129], mt[8][129], us[8][129];
    const int tid = threadIdx.x;
    const int base = blockIdx.x * 8;

    {
        int r = tid >> 5, c0 = (tid & 31) * 4;
        int row = base + r;
        float4 a = make_float4(0.f, 0.f, 0.f, 0.f);
        float4 bt = a, u4 = a;
        if (row < nrows) {
            a  = *reinterpret_cast<const float4*>(mean_i + (size_t)row * 128 + c0);
            bt = *reinterpret_cast<const float4*>(mean_t + (size_t)row * 128 + c0);
            u4 = *reinterpret_cast<const float4*>(U      + (size_t)row * 128 + c0);
        }
        mi[r][c0 + 0] = a.x;  mi[r][c0 + 1] = a.y;
        mi[r][c0 + 2] = a.z;  mi[r][c0 + 3] = a.w;
        mt[r][c0 + 0] = bt.x; mt[r][c0 + 1] = bt.y;
        mt[r][c0 + 2] = bt.z; mt[r][c0 + 3] = bt.w;
        us[r][c0 + 0] = u4.x; us[r][c0 + 1] = u4.y;
        us[r][c0 + 2] = u4.z; us[r][c0 + 3] = u4.w;
    }
    __syncthreads();

    const int c  = tid & 127;
    const int rg = tid >> 7;
    float acc0 = 0.f, acc1 = 0.f, acc2 = 0.f, acc3 = 0.f;
    #pragma unroll 2
    for (int k = 0; k < 128; ++k) {
        float w1 = Wl_i[k * 128 + c];
        float w2 = Wl_t[k * 128 + c];
        float w3 = Wr_s[k * 128 + c];
        acc0 += mi[rg + 0][k] * w1 + mt[rg + 0][k] * w2 + us[rg + 0][k] * w3;
        acc1 += mi[rg + 2][k] * w1 + mt[rg + 2][k] * w2 + us[rg + 2][k] * w3;
        acc2 += mi[rg + 4][k] * w1 + mt[rg + 4][k] * w2 + us[rg + 4][k] * w3;
        acc3 += mi[rg + 6][k] * w1 + mt[rg + 6][k] * w2 + us[rg + 6][k] * w3;
    }
    float bv = bsum[c];
    int r0 = base + rg;
    if (r0 + 0 < nrows) out[(size_t)(r0 + 0) * 128 + c] = fmaxf(acc0 + bv, 0.f);
    if (r0 + 2 < nrows) out[(size_t)(r0 + 2) * 128 + c] = fmaxf(acc1 + bv, 0.f);
    if (r0 + 4 < nrows) out[(size_t)(r0 + 4) * 128 + c] = fmaxf(acc2 + bv, 0.f);
    if (r0 + 6 < nrows) out[(size_t)(r0 + 6) * 128 + c] = fmaxf(acc3 + bv, 0.f);
}

extern "C" void kernel_launch(void* const* d_in, const int* in_sizes, int n_in,
                              void* d_out, int out_size, void* d_ws, size_t ws_size,
                              hipStream_t stream) {
    const float* x_user  = (const float*)d_in[0];
    const float* x_image = (const float*)d_in[1];
    const float* x_text  = (const float*)d_in[2];
    const int*   edge_i  = (const int*)d_in[3];
    const int*   edge_t  = (const int*)d_in[4];
    const float* W_user  = (const float*)d_in[5];
    const float* b_user  = (const float*)d_in[6];
    const float* Wl_img  = (const float*)d_in[7];
    const float* Wr_img  = (const float*)d_in[9];
    const float* bl_img  = (const float*)d_in[8];
    const float* Wl_txt  = (const float*)d_in[10];
    const float* bl_txt  = (const float*)d_in[11];
    const float* Wr_txt  = (const float*)d_in[12];

    const int N = in_sizes[0] / 256;   // 100000 nodes per type
    const int E = in_sizes[3] / 2;     // 800000 edges per relation
    const int NB = (N + SCAN_CHUNK - 1) / SCAN_CHUNK;

    float* ws     = (float*)d_ws;
    float* u      = ws;                           // N*128
    float* mean_i = u      + (size_t)N * 128;     // N*128
    float* mean_t = mean_i + (size_t)N * 128;     // N*128
    float* Wr_s   = mean_t + (size_t)N * 128;     // 128*128
    float* bsum   = Wr_s   + 128 * 128;           // 128
    int*   deg    = (int*)(bsum + 128);           // N (doubles as cursor)
    int*   rowptr = deg + N;                      // N+1
    int*   bscan  = rowptr + (N + 1);             // NB
    int*   col    = bscan + ((NB + 31) & ~31);    // E

    k_combine<<<(128 * 128 + 255) / 256, 256, 0, stream>>>(
        Wr_img, Wr_txt, bl_img, bl_txt, Wr_s, bsum);

    k_user_gemm<<<(N + 7) / 8, 256, 0, stream>>>(x_user, W_user, b_user, u, N);

    const int egrid = (E + 255) / 256;
    const int ggrid = (N * 32 + 255) / 256;

    // ---- relation image -> user ----
    hipMemsetAsync(deg, 0, (size_t)N * sizeof(int), stream);
    k_hist<<<egrid, 256, 0, stream>>>(edge_i, deg, E);
    k_scan1<<<NB, 256, 0, stream>>>(deg, bscan, N);
    k_scan2<<<1, 64, 0, stream>>>(bscan, NB, rowptr, N, E);
    k_scan3<<<NB, 256, 0, stream>>>(deg, rowptr, bscan, N);
    k_scatter<<<egrid, 256, 0, stream>>>(edge_i, deg, col, E);
    k_gather_mean<<<ggrid, 256, 0, stream>>>(x_image, rowptr, col, mean_i, N);

    // ---- relation text -> user (reuse CSR scratch) ----
    hipMemsetAsync(deg, 0, (size_t)N * sizeof(int), stream);
    k_hist<<<egrid, 256, 0, stream>>>(edge_t, deg, E);
    k_scan1<<<NB, 256, 0, stream>>>(deg, bscan, N);
    k_scan2<<<1, 64, 0, stream>>>(bscan, NB, rowptr, N, E);
    k_scan3<<<NB, 256, 0, stream>>>(deg, rowptr, bscan, N);
    k_scatter<<<egrid, 256, 0, stream>>>(edge_t, deg, col, E);
    k_gather_mean<<<ggrid, 256, 0, stream>>>(x_text, rowptr, col, mean_t, N);

    k_final<<<(N + 7) / 8, 256, 0, stream>>>(
        mean_i, mean_t, u, Wl_img, Wl_txt, Wr_s, bsum,
        (float*)d_out, N);
}

// Round 3
// 454.245 us; speedup vs baseline: 7.3228x; 1.8314x over previous
//
#include <hip/hip_runtime.h>

// ---------------------------------------------------------------------------
// HeteroGNN, bf16-MFMA edition.
//   u   = bf16( x_user @ W_user + b_user )                      [MFMA, K=256]
//   out = relu( [mean_i | mean_t | u] @ [Wl_i; Wl_t; Wr_i+Wr_t] + bsum )
//                                                               [MFMA, K=384]
// Aggregation: on-the-fly CSR (hist/scan/scatter) + atomic-free gather-mean
// writing bf16 means.
// MFMA fragment mapping (16x16x32_bf16): A: row=lane&15, k=(lane>>4)*8+j;
// B: col=lane&15, same k; D: col=lane&15, row=(lane>>4)*4+reg  [m89-verified].
// ---------------------------------------------------------------------------

#define SCAN_CHUNK 1024

typedef __attribute__((ext_vector_type(8))) short bf16x8;
typedef __attribute__((ext_vector_type(4))) float f32x4;

__device__ __forceinline__ ushort f2b(float x) {
    union { float f; unsigned u; } v; v.f = x;
    unsigned r = (v.u + 0x7FFF + ((v.u >> 16) & 1)) >> 16;   // RNE
    return (ushort)r;
}

// ---- pack W_user [256x128] into fragment order (8 ksteps x 8 cf x 64 lanes x 8) ----
__global__ __launch_bounds__(256) void k_pack_user(const float* __restrict__ W,
                                                   ushort* __restrict__ Bp) {
    int i = blockIdx.x * 256 + threadIdx.x;          // 32768 threads
    int j = i & 7, lane = (i >> 3) & 63, cf = (i >> 9) & 7, ks = i >> 12;
    int kk = ks * 32 + (lane >> 4) * 8 + j;
    int col = cf * 16 + (lane & 15);
    Bp[i] = f2b(W[kk * 128 + col]);
}

// ---- pack [Wl_i; Wl_t; Wr_i+Wr_t] (384x128) + bsum ----
__global__ __launch_bounds__(256) void k_pack_final(
        const float* __restrict__ Wl_i, const float* __restrict__ Wl_t,
        const float* __restrict__ Wr_i, const float* __restrict__ Wr_t,
        const float* __restrict__ bl_i, const float* __restrict__ bl_t,
        ushort* __restrict__ Bp, float* __restrict__ bsum) {
    int i = blockIdx.x * 256 + threadIdx.x;          // 49152 threads
    int j = i & 7, lane = (i >> 3) & 63, cf = (i >> 9) & 7, ks = i >> 12;
    int kk = ks * 32 + (lane >> 4) * 8 + j;
    int col = cf * 16 + (lane & 15);
    float v;
    if (kk < 128)       v = Wl_i[kk * 128 + col];
    else if (kk < 256)  v = Wl_t[(kk - 128) * 128 + col];
    else                v = Wr_i[(kk - 256) * 128 + col] + Wr_t[(kk - 256) * 128 + col];
    Bp[i] = f2b(v);
    if (i < 128) bsum[i] = bl_i[i] + bl_t[i];
}

// ---- x_user f32 -> bf16 ----
__global__ __launch_bounds__(256) void k_convert(const float* __restrict__ X,
                                                 ushort* __restrict__ Xb, int n4) {
    int i = blockIdx.x * 256 + threadIdx.x;
    if (i >= n4) return;
    float4 v = *reinterpret_cast<const float4*>(X + (size_t)i * 4);
    ushort4 o; o.x = f2b(v.x); o.y = f2b(v.y); o.z = f2b(v.z); o.w = f2b(v.w);
    *reinterpret_cast<ushort4*>(Xb + (size_t)i * 4) = o;
}

// ---- u = bf16( Xb[N,256] @ Wpack + b ) : MFMA ----
__global__ __launch_bounds__(256) void k_user_mfma(
        const ushort* __restrict__ Xb, const ushort* __restrict__ Bp,
        const float* __restrict__ b, ushort* __restrict__ U, int N) {
    const int tid = threadIdx.x;
    const int wid = tid >> 6, lane = tid & 63;
    const int rowA = blockIdx.x * 64 + wid * 16 + (lane & 15);
    const int rA = min(rowA, N - 1);
    const int kh = (lane >> 4) * 8;
    f32x4 acc[8] = {};
    #pragma unroll
    for (int ks = 0; ks < 8; ++ks) {
        bf16x8 a = *reinterpret_cast<const bf16x8*>(Xb + (size_t)rA * 256 + ks * 32 + kh);
        #pragma unroll
        for (int cf = 0; cf < 8; ++cf) {
            bf16x8 bb = *reinterpret_cast<const bf16x8*>(Bp + ((ks * 8 + cf) * 64 + lane) * 8);
            acc[cf] = __builtin_amdgcn_mfma_f32_16x16x32_bf16(a, bb, acc[cf], 0, 0, 0);
        }
    }
    const int col0 = lane & 15;
    const int rbase = blockIdx.x * 64 + wid * 16 + (lane >> 4) * 4;
    #pragma unroll
    for (int cf = 0; cf < 8; ++cf) {
        int col = cf * 16 + col0;
        float bv = b[col];
        #pragma unroll
        for (int r = 0; r < 4; ++r) {
            int row = rbase + r;
            if (row < N) U[(size_t)row * 128 + col] = f2b(acc[cf][r] + bv);
        }
    }
}

// ---- CSR build: histogram of dst ----
__global__ __launch_bounds__(256) void k_hist(const int* __restrict__ edge,
                                              int* __restrict__ deg, int E) {
    int e = blockIdx.x * 256 + threadIdx.x;
    if (e < E) atomicAdd(&deg[edge[E + e]], 1);
}

// ---- scan pass 1: per-chunk sums ----
__global__ __launch_bounds__(256) void k_scan1(const int* __restrict__ deg,
                                               int* __restrict__ bsum, int N) {
    __shared__ int sh[256];
    int base = blockIdx.x * SCAN_CHUNK;
    int t = threadIdx.x;
    int s = 0;
    #pragma unroll
    for (int j = 0; j < 4; ++j) {
        int idx = base + j * 256 + t;
        if (idx < N) s += deg[idx];
    }
    sh[t] = s; __syncthreads();
    for (int off = 128; off > 0; off >>= 1) {
        if (t < off) sh[t] += sh[t + off];
        __syncthreads();
    }
    if (t == 0) bsum[blockIdx.x] = sh[0];
}

// ---- scan pass 2: serial exclusive scan of chunk sums ----
__global__ void k_scan2(int* __restrict__ bsum, int nb,
                        int* __restrict__ rowptr, int N, int E) {
    if (threadIdx.x == 0 && blockIdx.x == 0) {
        int run = 0;
        for (int b = 0; b < nb; ++b) { int v = bsum[b]; bsum[b] = run; run += v; }
        rowptr[N] = E;
    }
}

// ---- scan pass 3: intra-chunk exclusive scan; rowptr + cursor ----
__global__ __launch_bounds__(256) void k_scan3(int* __restrict__ deg,
                                               int* __restrict__ rowptr,
                                               const int* __restrict__ bsum, int N) {
    __shared__ int sh[256];
    int base = blockIdx.x * SCAN_CHUNK;
    int t = threadIdx.x;
    int v[4]; int s = 0;
    #pragma unroll
    for (int j = 0; j < 4; ++j) {
        int idx = base + 4 * t + j;
        v[j] = (idx < N) ? deg[idx] : 0;
        s += v[j];
    }
    sh[t] = s; __syncthreads();
    for (int off = 1; off < 256; off <<= 1) {
        int add = (t >= off) ? sh[t - off] : 0;
        __syncthreads();
        sh[t] += add;
        __syncthreads();
    }
    int run = sh[t] - s + bsum[blockIdx.x];
    #pragma unroll
    for (int j = 0; j < 4; ++j) {
        int idx = base + 4 * t + j;
        if (idx < N) { rowptr[idx] = run; deg[idx] = run; run += v[j]; }
    }
}

// ---- scatter: place src indices into CSR buckets ----
__global__ __launch_bounds__(256) void k_scatter(const int* __restrict__ edge,
                                                 int* __restrict__ cursor,
                                                 int* __restrict__ col, int E) {
    int e = blockIdx.x * 256 + threadIdx.x;
    if (e < E) {
        int d = edge[E + e];
        int p = atomicAdd(&cursor[d], 1);
        col[p] = edge[e];
    }
}

// ---- gather-mean: 32 lanes per destination node; bf16 output ----
__global__ __launch_bounds__(256) void k_gather_mean(
        const float* __restrict__ xsrc, const int* __restrict__ rowptr,
        const int* __restrict__ col, ushort* __restrict__ mean, int N) {
    int t = blockIdx.x * 256 + threadIdx.x;
    int node = t >> 5, lane = t & 31;
    if (node >= N) return;
    int beg = rowptr[node], end = rowptr[node + 1];
    float ax = 0.f, ay = 0.f, az = 0.f, aw = 0.f;
    for (int j = beg; j < end; ++j) {
        int s = col[j];
        float4 v = *reinterpret_cast<const float4*>(xsrc + (size_t)s * 128 + lane * 4);
        ax += v.x; ay += v.y; az += v.z; aw += v.w;
    }
    float r = (end > beg) ? 1.0f / (float)(end - beg) : 0.0f;
    ushort4 o; o.x = f2b(ax * r); o.y = f2b(ay * r); o.z = f2b(az * r); o.w = f2b(aw * r);
    *reinterpret_cast<ushort4*>(mean + (size_t)node * 128 + lane * 4) = o;
}

// ---- out = relu( [mi|mt|u](bf16, K=384) @ Bpack + bsum ) : MFMA ----
__global__ __launch_bounds__(256) void k_final_mfma(
        const ushort* __restrict__ mi, const ushort* __restrict__ mt,
        const ushort* __restrict__ ub, const ushort* __restrict__ Bp,
        const float* __restrict__ bsum, float* __restrict__ out, int N) {
    const int tid = threadIdx.x;
    const int wid = tid >> 6, lane = tid & 63;
    const int rowA = blockIdx.x * 64 + wid * 16 + (lane & 15);
    const int rA = min(rowA, N - 1);
    const int kh = (lane >> 4) * 8;
    f32x4 acc[8] = {};
    #pragma unroll
    for (int ks = 0; ks < 12; ++ks) {
        const ushort* s = (ks < 4) ? mi : (ks < 8) ? mt : ub;
        bf16x8 a = *reinterpret_cast<const bf16x8*>(s + (size_t)rA * 128 + (ks & 3) * 32 + kh);
        #pragma unroll
        for (int cf = 0; cf < 8; ++cf) {
            bf16x8 bb = *reinterpret_cast<const bf16x8*>(Bp + ((ks * 8 + cf) * 64 + lane) * 8);
            acc[cf] = __builtin_amdgcn_mfma_f32_16x16x32_bf16(a, bb, acc[cf], 0, 0, 0);
        }
    }
    const int col0 = lane & 15;
    const int rbase = blockIdx.x * 64 + wid * 16 + (lane >> 4) * 4;
    #pragma unroll
    for (int cf = 0; cf < 8; ++cf) {
        int col = cf * 16 + col0;
        float bv = bsum[col];
        #pragma unroll
        for (int r = 0; r < 4; ++r) {
            int row = rbase + r;
            if (row < N) out[(size_t)row * 128 + col] = fmaxf(acc[cf][r] + bv, 0.f);
        }
    }
}

extern "C" void kernel_launch(void* const* d_in, const int* in_sizes, int n_in,
                              void* d_out, int out_size, void* d_ws, size_t ws_size,
                              hipStream_t stream) {
    const float* x_user  = (const float*)d_in[0];
    const float* x_image = (const float*)d_in[1];
    const float* x_text  = (const float*)d_in[2];
    const int*   edge_i  = (const int*)d_in[3];
    const int*   edge_t  = (const int*)d_in[4];
    const float* W_user  = (const float*)d_in[5];
    const float* b_user  = (const float*)d_in[6];
    const float* Wl_img  = (const float*)d_in[7];
    const float* bl_img  = (const float*)d_in[8];
    const float* Wr_img  = (const float*)d_in[9];
    const float* Wl_txt  = (const float*)d_in[10];
    const float* bl_txt  = (const float*)d_in[11];
    const float* Wr_txt  = (const float*)d_in[12];

    const int N = in_sizes[0] / 256;   // 100000 nodes per type
    const int E = in_sizes[3] / 2;     // 800000 edges per relation
    const int NB = (N + SCAN_CHUNK - 1) / SCAN_CHUNK;

    ushort* xu   = (ushort*)d_ws;                  // N*256
    ushort* ub   = xu + (size_t)N * 256;           // N*128
    ushort* mi   = ub + (size_t)N * 128;           // N*128
    ushort* mt   = mi + (size_t)N * 128;           // N*128
    ushort* Bpu  = mt + (size_t)N * 128;           // 32768
    ushort* Bpf  = Bpu + 32768;                    // 49152
    float*  bsum = (float*)(Bpf + 49152);          // 128
    int*    deg    = (int*)(bsum + 128);           // N (doubles as cursor)
    int*    rowptr = deg + N;                      // N+1
    int*    bscan  = rowptr + (N + 1);             // NB
    int*    col    = bscan + ((NB + 31) & ~31);    // E

    k_pack_user<<<32768 / 256, 256, 0, stream>>>(W_user, Bpu);
    k_pack_final<<<49152 / 256, 256, 0, stream>>>(
        Wl_img, Wl_txt, Wr_img, Wr_txt, bl_img, bl_txt, Bpf, bsum);

    k_convert<<<(N * 64 + 255) / 256, 256, 0, stream>>>(x_user, xu, N * 64);
    k_user_mfma<<<(N + 63) / 64, 256, 0, stream>>>(xu, Bpu, b_user, ub, N);

    const int egrid = (E + 255) / 256;
    const int ggrid = (N * 32 + 255) / 256;

    // ---- relation image -> user ----
    hipMemsetAsync(deg, 0, (size_t)N * sizeof(int), stream);
    k_hist<<<egrid, 256, 0, stream>>>(edge_i, deg, E);
    k_scan1<<<NB, 256, 0, stream>>>(deg, bscan, N);
    k_scan2<<<1, 64, 0, stream>>>(bscan, NB, rowptr, N, E);
    k_scan3<<<NB, 256, 0, stream>>>(deg, rowptr, bscan, N);
    k_scatter<<<egrid, 256, 0, stream>>>(edge_i, deg, col, E);
    k_gather_mean<<<ggrid, 256, 0, stream>>>(x_image, rowptr, col, mi, N);

    // ---- relation text -> user (reuse CSR scratch) ----
    hipMemsetAsync(deg, 0, (size_t)N * sizeof(int), stream);
    k_hist<<<egrid, 256, 0, stream>>>(edge_t, deg, E);
    k_scan1<<<NB, 256, 0, stream>>>(deg, bscan, N);
    k_scan2<<<1, 64, 0, stream>>>(bscan, NB, rowptr, N, E);
    k_scan3<<<NB, 256, 0, stream>>>(deg, rowptr, bscan, N);
    k_scatter<<<egrid, 256, 0, stream>>>(edge_t, deg, col, E);
    k_gather_mean<<<ggrid, 256, 0, stream>>>(x_text, rowptr, col, mt, N);

    k_final_mfma<<<(N + 63) / 64, 256, 0, stream>>>(
        mi, mt, ub, Bpf, bsum, (float*)d_out, N);
}

// Round 4
// 382.725 us; speedup vs baseline: 8.6912x; 1.1869x over previous
//
#include <hip/hip_runtime.h>

// ---------------------------------------------------------------------------
// HeteroGNN, bf16-MFMA edition, round 4.
//   u   = bf16( x_user @ W_user + b_user )          [MFMA K=256, inline f32->bf16]
//   out = relu( [mean_i | mean_t | u] @ [Wl_i; Wl_t; Wr_i+Wr_t] + bsum )  [MFMA K=384]
// Aggregation: merged 2-relation CSR (hist/scan/scatter over 2N) +
// atomic-free gather-mean over bf16-converted source tables (256 B/row).
// MFMA 16x16x32_bf16 mapping: A: row=lane&15, k=(lane>>4)*8+j; B: col=lane&15;
// D: col=lane&15, row=(lane>>4)*4+reg  [m89-verified].
// ---------------------------------------------------------------------------

#define SCAN_CHUNK 1024

typedef __attribute__((ext_vector_type(8))) short bf16x8;
typedef __attribute__((ext_vector_type(8))) unsigned short u16x8;
typedef __attribute__((ext_vector_type(4))) float f32x4;

__device__ __forceinline__ ushort f2b(float x) {
    union { float f; unsigned u; } v; v.f = x;
    unsigned r = (v.u + 0x7FFF + ((v.u >> 16) & 1)) >> 16;   // RNE
    return (ushort)r;
}
__device__ __forceinline__ float b2f(ushort u) {
    union { unsigned u; float f; } v; v.u = (unsigned)u << 16;
    return v.f;
}

// ---- pack W_user [256x128] into fragment order ----
__global__ __launch_bounds__(256) void k_pack_user(const float* __restrict__ W,
                                                   ushort* __restrict__ Bp) {
    int i = blockIdx.x * 256 + threadIdx.x;          // 32768 threads
    int j = i & 7, lane = (i >> 3) & 63, cf = (i >> 9) & 7, ks = i >> 12;
    int kk = ks * 32 + (lane >> 4) * 8 + j;
    int col = cf * 16 + (lane & 15);
    Bp[i] = f2b(W[kk * 128 + col]);
}

// ---- pack [Wl_i; Wl_t; Wr_i+Wr_t] (384x128) + bsum ----
__global__ __launch_bounds__(256) void k_pack_final(
        const float* __restrict__ Wl_i, const float* __restrict__ Wl_t,
        const float* __restrict__ Wr_i, const float* __restrict__ Wr_t,
        const float* __restrict__ bl_i, const float* __restrict__ bl_t,
        ushort* __restrict__ Bp, float* __restrict__ bsum) {
    int i = blockIdx.x * 256 + threadIdx.x;          // 49152 threads
    int j = i & 7, lane = (i >> 3) & 63, cf = (i >> 9) & 7, ks = i >> 12;
    int kk = ks * 32 + (lane >> 4) * 8 + j;
    int col = cf * 16 + (lane & 15);
    float v;
    if (kk < 128)       v = Wl_i[kk * 128 + col];
    else if (kk < 256)  v = Wl_t[(kk - 128) * 128 + col];
    else                v = Wr_i[(kk - 256) * 128 + col] + Wr_t[(kk - 256) * 128 + col];
    Bp[i] = f2b(v);
    if (i < 128) bsum[i] = bl_i[i] + bl_t[i];
}

// ---- x_image / x_text f32 -> bf16 (grid.y selects table) ----
__global__ __launch_bounds__(256) void k_convert2(
        const float* __restrict__ xi, const float* __restrict__ xt,
        ushort* __restrict__ xib, ushort* __restrict__ xtb, int n8) {
    int i = blockIdx.x * 256 + threadIdx.x;
    if (i >= n8) return;
    const float* src = blockIdx.y ? xt : xi;
    ushort* dst = blockIdx.y ? xtb : xib;
    float4 f0 = *reinterpret_cast<const float4*>(src + (size_t)i * 8);
    float4 f1 = *reinterpret_cast<const float4*>(src + (size_t)i * 8 + 4);
    u16x8 o;
    o[0] = f2b(f0.x); o[1] = f2b(f0.y); o[2] = f2b(f0.z); o[3] = f2b(f0.w);
    o[4] = f2b(f1.x); o[5] = f2b(f1.y); o[6] = f2b(f1.z); o[7] = f2b(f1.w);
    *reinterpret_cast<u16x8*>(dst + (size_t)i * 8) = o;
}

// ---- u = bf16( x_user(f32)[N,256] @ Wpack + b ) : MFMA, inline convert ----
__global__ __launch_bounds__(256) void k_user_mfma(
        const float* __restrict__ X, const ushort* __restrict__ Bp,
        const float* __restrict__ b, ushort* __restrict__ U, int N) {
    const int tid = threadIdx.x;
    const int wid = tid >> 6, lane = tid & 63;
    const int rowA = blockIdx.x * 64 + wid * 16 + (lane & 15);
    const int rA = min(rowA, N - 1);
    const int kh = (lane >> 4) * 8;
    const float* Xr = X + (size_t)rA * 256;
    f32x4 acc[8] = {};
    #pragma unroll
    for (int ks = 0; ks < 8; ++ks) {
        float4 f0 = *reinterpret_cast<const float4*>(Xr + ks * 32 + kh);
        float4 f1 = *reinterpret_cast<const float4*>(Xr + ks * 32 + kh + 4);
        bf16x8 a;
        a[0] = (short)f2b(f0.x); a[1] = (short)f2b(f0.y);
        a[2] = (short)f2b(f0.z); a[3] = (short)f2b(f0.w);
        a[4] = (short)f2b(f1.x); a[5] = (short)f2b(f1.y);
        a[6] = (short)f2b(f1.z); a[7] = (short)f2b(f1.w);
        #pragma unroll
        for (int cf = 0; cf < 8; ++cf) {
            bf16x8 bb = *reinterpret_cast<const bf16x8*>(Bp + ((ks * 8 + cf) * 64 + lane) * 8);
            acc[cf] = __builtin_amdgcn_mfma_f32_16x16x32_bf16(a, bb, acc[cf], 0, 0, 0);
        }
    }
    const int col0 = lane & 15;
    const int rbase = blockIdx.x * 64 + wid * 16 + (lane >> 4) * 4;
    #pragma unroll
    for (int cf = 0; cf < 8; ++cf) {
        int col = cf * 16 + col0;
        float bv = b[col];
        #pragma unroll
        for (int r = 0; r < 4; ++r) {
            int row = rbase + r;
            if (row < N) U[(size_t)row * 128 + col] = f2b(acc[cf][r] + bv);
        }
    }
}

// ---- merged histogram: deg[y*N + dst]++ for both relations ----
__global__ __launch_bounds__(256) void k_hist2(const int* __restrict__ edge_i,
                                               const int* __restrict__ edge_t,
                                               int* __restrict__ deg, int N, int E) {
    int e = blockIdx.x * 256 + threadIdx.x;
    if (e >= E) return;
    const int* eg = blockIdx.y ? edge_t : edge_i;
    atomicAdd(&deg[blockIdx.y * N + eg[E + e]], 1);
}

// ---- scan pass 1: per-chunk sums (over M = 2N) ----
__global__ __launch_bounds__(256) void k_scan1(const int* __restrict__ deg,
                                               int* __restrict__ bsum, int M) {
    __shared__ int sh[256];
    int base = blockIdx.x * SCAN_CHUNK;
    int t = threadIdx.x;
    int s = 0;
    #pragma unroll
    for (int j = 0; j < 4; ++j) {
        int idx = base + j * 256 + t;
        if (idx < M) s += deg[idx];
    }
    sh[t] = s; __syncthreads();
    for (int off = 128; off > 0; off >>= 1) {
        if (t < off) sh[t] += sh[t + off];
        __syncthreads();
    }
    if (t == 0) bsum[blockIdx.x] = sh[0];
}

// ---- scan pass 2: parallel exclusive scan of chunk sums (nb <= 256) ----
__global__ __launch_bounds__(256) void k_scan2(int* __restrict__ bsum, int nb,
                                               int* __restrict__ rowptr, int M, int Etot) {
    __shared__ int sh[256];
    int t = threadIdx.x;
    int v = (t < nb) ? bsum[t] : 0;
    sh[t] = v; __syncthreads();
    for (int off = 1; off < 256; off <<= 1) {
        int add = (t >= off) ? sh[t - off] : 0;
        __syncthreads();
        sh[t] += add;
        __syncthreads();
    }
    if (t < nb) bsum[t] = sh[t] - v;       // exclusive
    if (t == 0) rowptr[M] = Etot;
}

// ---- scan pass 3: intra-chunk exclusive scan; rowptr + cursor ----
__global__ __launch_bounds__(256) void k_scan3(int* __restrict__ deg,
                                               int* __restrict__ rowptr,
                                               const int* __restrict__ bsum, int M) {
    __shared__ int sh[256];
    int base = blockIdx.x * SCAN_CHUNK;
    int t = threadIdx.x;
    int v[4]; int s = 0;
    #pragma unroll
    for (int j = 0; j < 4; ++j) {
        int idx = base + 4 * t + j;
        v[j] = (idx < M) ? deg[idx] : 0;
        s += v[j];
    }
    sh[t] = s; __syncthreads();
    for (int off = 1; off < 256; off <<= 1) {
        int add = (t >= off) ? sh[t - off] : 0;
        __syncthreads();
        sh[t] += add;
        __syncthreads();
    }
    int run = sh[t] - s + bsum[blockIdx.x];
    #pragma unroll
    for (int j = 0; j < 4; ++j) {
        int idx = base + 4 * t + j;
        if (idx < M) { rowptr[idx] = run; deg[idx] = run; run += v[j]; }
    }
}

// ---- merged scatter into single col[2E] ----
__global__ __launch_bounds__(256) void k_scatter2(const int* __restrict__ edge_i,
                                                  const int* __restrict__ edge_t,
                                                  int* __restrict__ cursor,
                                                  int* __restrict__ col, int N, int E) {
    int e = blockIdx.x * 256 + threadIdx.x;
    if (e >= E) return;
    const int* eg = blockIdx.y ? edge_t : edge_i;
    int d = blockIdx.y * N + eg[E + e];
    int p = atomicAdd(&cursor[d], 1);
    col[p] = eg[e];
}

// ---- gather-mean: 16 lanes per node, bf16 rows (256 B), both relations ----
__global__ __launch_bounds__(256) void k_gather_mean(
        const ushort* __restrict__ xib, const ushort* __restrict__ xtb,
        const int* __restrict__ rowptr, const int* __restrict__ col,
        ushort* __restrict__ mi, ushort* __restrict__ mt, int N) {
    int t = blockIdx.x * 256 + threadIdx.x;
    int node = t >> 4, lane = t & 15;
    if (node >= N) return;
    int rel = blockIdx.y;
    const ushort* xs = rel ? xtb : xib;
    ushort* mean = rel ? mt : mi;
    int rb = rel * N + node;
    int beg = rowptr[rb], end = rowptr[rb + 1];
    float a0 = 0.f, a1 = 0.f, a2 = 0.f, a3 = 0.f,
          a4 = 0.f, a5 = 0.f, a6 = 0.f, a7 = 0.f;
    int j = beg;
    for (; j + 1 < end; j += 2) {
        int s0 = col[j], s1 = col[j + 1];
        u16x8 v0 = *reinterpret_cast<const u16x8*>(xs + (size_t)s0 * 128 + lane * 8);
        u16x8 v1 = *reinterpret_cast<const u16x8*>(xs + (size_t)s1 * 128 + lane * 8);
        a0 += b2f(v0[0]) + b2f(v1[0]);  a1 += b2f(v0[1]) + b2f(v1[1]);
        a2 += b2f(v0[2]) + b2f(v1[2]);  a3 += b2f(v0[3]) + b2f(v1[3]);
        a4 += b2f(v0[4]) + b2f(v1[4]);  a5 += b2f(v0[5]) + b2f(v1[5]);
        a6 += b2f(v0[6]) + b2f(v1[6]);  a7 += b2f(v0[7]) + b2f(v1[7]);
    }
    if (j < end) {
        int s0 = col[j];
        u16x8 v0 = *reinterpret_cast<const u16x8*>(xs + (size_t)s0 * 128 + lane * 8);
        a0 += b2f(v0[0]); a1 += b2f(v0[1]); a2 += b2f(v0[2]); a3 += b2f(v0[3]);
        a4 += b2f(v0[4]); a5 += b2f(v0[5]); a6 += b2f(v0[6]); a7 += b2f(v0[7]);
    }
    float r = (end > beg) ? 1.0f / (float)(end - beg) : 0.0f;
    u16x8 o;
    o[0] = f2b(a0 * r); o[1] = f2b(a1 * r); o[2] = f2b(a2 * r); o[3] = f2b(a3 * r);
    o[4] = f2b(a4 * r); o[5] = f2b(a5 * r); o[6] = f2b(a6 * r); o[7] = f2b(a7 * r);
    *reinterpret_cast<u16x8*>(mean + (size_t)node * 128 + lane * 8) = o;
}

// ---- out = relu( [mi|mt|u](bf16, K=384) @ Bpack + bsum ) : MFMA ----
__global__ __launch_bounds__(256) void k_final_mfma(
        const ushort* __restrict__ mi, const ushort* __restrict__ mt,
        const ushort* __restrict__ ub, const ushort* __restrict__ Bp,
        const float* __restrict__ bsum, float* __restrict__ out, int N) {
    const int tid = threadIdx.x;
    const int wid = tid >> 6, lane = tid & 63;
    const int rowA = blockIdx.x * 64 + wid * 16 + (lane & 15);
    const int rA = min(rowA, N - 1);
    const int kh = (lane >> 4) * 8;
    f32x4 acc[8] = {};
    #pragma unroll
    for (int ks = 0; ks < 12; ++ks) {
        const ushort* s = (ks < 4) ? mi : (ks < 8) ? mt : ub;
        bf16x8 a = *reinterpret_cast<const bf16x8*>(s + (size_t)rA * 128 + (ks & 3) * 32 + kh);
        #pragma unroll
        for (int cf = 0; cf < 8; ++cf) {
            bf16x8 bb = *reinterpret_cast<const bf16x8*>(Bp + ((ks * 8 + cf) * 64 + lane) * 8);
            acc[cf] = __builtin_amdgcn_mfma_f32_16x16x32_bf16(a, bb, acc[cf], 0, 0, 0);
        }
    }
    const int col0 = lane & 15;
    const int rbase = blockIdx.x * 64 + wid * 16 + (lane >> 4) * 4;
    #pragma unroll
    for (int cf = 0; cf < 8; ++cf) {
        int col = cf * 16 + col0;
        float bv = bsum[col];
        #pragma unroll
        for (int r = 0; r < 4; ++r) {
            int row = rbase + r;
            if (row < N) out[(size_t)row * 128 + col] = fmaxf(acc[cf][r] + bv, 0.f);
        }
    }
}

extern "C" void kernel_launch(void* const* d_in, const int* in_sizes, int n_in,
                              void* d_out, int out_size, void* d_ws, size_t ws_size,
                              hipStream_t stream) {
    const float* x_user  = (const float*)d_in[0];
    const float* x_image = (const float*)d_in[1];
    const float* x_text  = (const float*)d_in[2];
    const int*   edge_i  = (const int*)d_in[3];
    const int*   edge_t  = (const int*)d_in[4];
    const float* W_user  = (const float*)d_in[5];
    const float* b_user  = (const float*)d_in[6];
    const float* Wl_img  = (const float*)d_in[7];
    const float* bl_img  = (const float*)d_in[8];
    const float* Wr_img  = (const float*)d_in[9];
    const float* Wl_txt  = (const float*)d_in[10];
    const float* bl_txt  = (const float*)d_in[11];
    const float* Wr_txt  = (const float*)d_in[12];

    const int N = in_sizes[0] / 256;   // 100000 nodes per type
    const int E = in_sizes[3] / 2;     // 800000 edges per relation
    const int M = 2 * N;               // concatenated dst space
    const int NB = (M + SCAN_CHUNK - 1) / SCAN_CHUNK;   // <= 256

    ushort* xib  = (ushort*)d_ws;                  // N*128
    ushort* xtb  = xib + (size_t)N * 128;          // N*128
    ushort* ub   = xtb + (size_t)N * 128;          // N*128
    ushort* mi   = ub  + (size_t)N * 128;          // N*128
    ushort* mt   = mi  + (size_t)N * 128;          // N*128
    ushort* Bpu  = mt  + (size_t)N * 128;          // 32768
    ushort* Bpf  = Bpu + 32768;                    // 49152
    float*  bsum = (float*)(Bpf + 49152);          // 128
    int*    deg    = (int*)(bsum + 128);           // M (doubles as cursor)
    int*    rowptr = deg + M;                      // M+1
    int*    bscan  = rowptr + (M + 1);             // NB
    int*    col    = bscan + ((NB + 31) & ~31);    // 2E

    k_pack_user<<<32768 / 256, 256, 0, stream>>>(W_user, Bpu);
    k_pack_final<<<49152 / 256, 256, 0, stream>>>(
        Wl_img, Wl_txt, Wr_img, Wr_txt, bl_img, bl_txt, Bpf, bsum);

    // convert image/text tables to bf16 (both relations in one dispatch)
    {
        int n8 = N * 16;   // N*128/8
        dim3 g((n8 + 255) / 256, 2);
        k_convert2<<<g, 256, 0, stream>>>(x_image, x_text, xib, xtb, n8);
    }

    k_user_mfma<<<(N + 63) / 64, 256, 0, stream>>>(x_user, Bpu, b_user, ub, N);

    // ---- merged CSR build ----
    hipMemsetAsync(deg, 0, (size_t)M * sizeof(int), stream);
    {
        dim3 g((E + 255) / 256, 2);
        k_hist2<<<g, 256, 0, stream>>>(edge_i, edge_t, deg, N, E);
    }
    k_scan1<<<NB, 256, 0, stream>>>(deg, bscan, M);
    k_scan2<<<1, 256, 0, stream>>>(bscan, NB, rowptr, M, 2 * E);
    k_scan3<<<NB, 256, 0, stream>>>(deg, rowptr, bscan, M);
    {
        dim3 g((E + 255) / 256, 2);
        k_scatter2<<<g, 256, 0, stream>>>(edge_i, edge_t, deg, col, N, E);
    }

    // ---- gather means (both relations in one dispatch) ----
    {
        dim3 g((N * 16 + 255) / 256, 2);
        k_gather_mean<<<g, 256, 0, stream>>>(xib, xtb, rowptr, col, mi, mt, N);
    }

    k_final_mfma<<<(N + 63) / 64, 256, 0, stream>>>(
        mi, mt, ub, Bpf, bsum, (float*)d_out, N);
}

// Round 5
// 294.806 us; speedup vs baseline: 11.2832x; 1.2982x over previous
//
#include <hip/hip_runtime.h>

// ---------------------------------------------------------------------------
// HeteroGNN, bf16-MFMA, round 5.
//   u   = bf16( x_user @ W_user + b_user )          [MFMA K=256, inline cvt]
//   out = relu( [mean_i | mean_t | u] @ [Wl_i; Wl_t; Wr_i+Wr_t] + bsum )  [MFMA K=384]
// CSR: hist captures atomicAdd return as per-edge rank (rank-capture) ->
// scatter is atomic-free. Front phases (hist, user-GEMM, bf16 convert) fused
// into one block-range-partitioned dispatch for latency/BW overlap.
// MFMA 16x16x32_bf16 mapping: A: row=lane&15, k=(lane>>4)*8+j; B: col=lane&15;
// D: col=lane&15, row=(lane>>4)*4+reg  [m89-verified].
// ---------------------------------------------------------------------------

#define SCAN_CHUNK 1024

typedef __attribute__((ext_vector_type(8))) short bf16x8;
typedef __attribute__((ext_vector_type(8))) unsigned short u16x8;
typedef __attribute__((ext_vector_type(4))) float f32x4;

__device__ __forceinline__ ushort f2b(float x) {
    union { float f; unsigned u; } v; v.f = x;
    unsigned r = (v.u + 0x7FFF + ((v.u >> 16) & 1)) >> 16;   // RNE
    return (ushort)r;
}
__device__ __forceinline__ float b2f(ushort u) {
    union { unsigned u; float f; } v; v.u = (unsigned)u << 16;
    return v.f;
}

// ---- pack both weight blocks into MFMA fragment order + bsum ----
__global__ __launch_bounds__(256) void k_pack(
        const float* __restrict__ W_user,
        const float* __restrict__ Wl_i, const float* __restrict__ Wl_t,
        const float* __restrict__ Wr_i, const float* __restrict__ Wr_t,
        const float* __restrict__ bl_i, const float* __restrict__ bl_t,
        ushort* __restrict__ Bpu, ushort* __restrict__ Bpf, float* __restrict__ bsum) {
    int i = blockIdx.x * 256 + threadIdx.x;          // 81920 threads
    if (i < 32768) {
        int j = i & 7, lane = (i >> 3) & 63, cf = (i >> 9) & 7, ks = i >> 12;
        int kk = ks * 32 + (lane >> 4) * 8 + j;
        int col = cf * 16 + (lane & 15);
        Bpu[i] = f2b(W_user[kk * 128 + col]);
    } else {
        int i2 = i - 32768;                          // < 49152
        int j = i2 & 7, lane = (i2 >> 3) & 63, cf = (i2 >> 9) & 7, ks = i2 >> 12;
        int kk = ks * 32 + (lane >> 4) * 8 + j;
        int col = cf * 16 + (lane & 15);
        float v;
        if (kk < 128)       v = Wl_i[kk * 128 + col];
        else if (kk < 256)  v = Wl_t[(kk - 128) * 128 + col];
        else                v = Wr_i[(kk - 256) * 128 + col] + Wr_t[(kk - 256) * 128 + col];
        Bpf[i2] = f2b(v);
        if (i2 < 128) bsum[i2] = bl_i[i2] + bl_t[i2];
    }
}

// ---- fused front: [hist+rank | user-MFMA | convert] by block range ----
__global__ __launch_bounds__(256) void k_front(
        const float* __restrict__ x_user,
        const float* __restrict__ x_image, const float* __restrict__ x_text,
        const int* __restrict__ edge_i, const int* __restrict__ edge_t,
        const ushort* __restrict__ Bpu, const float* __restrict__ b_user,
        ushort* __restrict__ xib, ushort* __restrict__ xtb,
        ushort* __restrict__ U, int* __restrict__ deg, int* __restrict__ rank,
        int N, int E, int nbH, int nbU) {
    const int bid = blockIdx.x;
    const int tid = threadIdx.x;

    if (bid < 2 * nbH) {
        // ---------------- histogram + rank capture (4 edges/thread) ------
        int rel = (bid >= nbH) ? 1 : 0;
        int b = bid - rel * nbH;
        const int* eg = rel ? edge_t : edge_i;
        int* rk = rank + (size_t)rel * E;
        int* dg = deg + (size_t)rel * N;
        int e = b * 1024 + tid * 4;
        if (e + 3 < E) {
            int4 d4 = *reinterpret_cast<const int4*>(eg + E + e);
            int4 r4;
            r4.x = atomicAdd(&dg[d4.x], 1);
            r4.y = atomicAdd(&dg[d4.y], 1);
            r4.z = atomicAdd(&dg[d4.z], 1);
            r4.w = atomicAdd(&dg[d4.w], 1);
            *reinterpret_cast<int4*>(rk + e) = r4;
        } else {
            for (int j = 0; j < 4; ++j) {
                int ee = e + j;
                if (ee < E) rk[ee] = atomicAdd(&dg[eg[E + ee]], 1);
            }
        }
    } else if (bid < 2 * nbH + nbU) {
        // ---------------- u = bf16( x_user @ Wpack + b ) ------------------
        int bu = bid - 2 * nbH;
        const int wid = tid >> 6, lane = tid & 63;
        const int rowA = bu * 64 + wid * 16 + (lane & 15);
        const int rA = min(rowA, N - 1);
        const int kh = (lane >> 4) * 8;
        const float* Xr = x_user + (size_t)rA * 256;
        f32x4 acc[8] = {};
        #pragma unroll
        for (int ks = 0; ks < 8; ++ks) {
            float4 f0 = *reinterpret_cast<const float4*>(Xr + ks * 32 + kh);
            float4 f1 = *reinterpret_cast<const float4*>(Xr + ks * 32 + kh + 4);
            bf16x8 a;
            a[0] = (short)f2b(f0.x); a[1] = (short)f2b(f0.y);
            a[2] = (short)f2b(f0.z); a[3] = (short)f2b(f0.w);
            a[4] = (short)f2b(f1.x); a[5] = (short)f2b(f1.y);
            a[6] = (short)f2b(f1.z); a[7] = (short)f2b(f1.w);
            #pragma unroll
            for (int cf = 0; cf < 8; ++cf) {
                bf16x8 bb = *reinterpret_cast<const bf16x8*>(Bpu + ((ks * 8 + cf) * 64 + lane) * 8);
                acc[cf] = __builtin_amdgcn_mfma_f32_16x16x32_bf16(a, bb, acc[cf], 0, 0, 0);
            }
        }
        const int col0 = lane & 15;
        const int rbase = bu * 64 + wid * 16 + (lane >> 4) * 4;
        #pragma unroll
        for (int cf = 0; cf < 8; ++cf) {
            int col = cf * 16 + col0;
            float bv = b_user[col];
            #pragma unroll
            for (int r = 0; r < 4; ++r) {
                int row = rbase + r;
                if (row < N) U[(size_t)row * 128 + col] = f2b(acc[cf][r] + bv);
            }
        }
    } else {
        // ---------------- x_image/x_text f32 -> bf16 ----------------------
        int t = (bid - 2 * nbH - nbU) * 256 + tid;
        int n8 = N * 16;                       // elems-of-8 per table
        if (t >= 2 * n8) return;
        const float* src = (t < n8) ? x_image : x_text;
        ushort* dst = (t < n8) ? xib : xtb;
        int i = (t < n8) ? t : t - n8;
        float4 f0 = *reinterpret_cast<const float4*>(src + (size_t)i * 8);
        float4 f1 = *reinterpret_cast<const float4*>(src + (size_t)i * 8 + 4);
        u16x8 o;
        o[0] = f2b(f0.x); o[1] = f2b(f0.y); o[2] = f2b(f0.z); o[3] = f2b(f0.w);
        o[4] = f2b(f1.x); o[5] = f2b(f1.y); o[6] = f2b(f1.z); o[7] = f2b(f1.w);
        *reinterpret_cast<u16x8*>(dst + (size_t)i * 8) = o;
    }
}

// ---- scan pass 1: per-chunk sums (over M = 2N) ----
__global__ __launch_bounds__(256) void k_scan1(const int* __restrict__ deg,
                                               int* __restrict__ bsum, int M) {
    __shared__ int sh[256];
    int base = blockIdx.x * SCAN_CHUNK;
    int t = threadIdx.x;
    int s = 0;
    #pragma unroll
    for (int j = 0; j < 4; ++j) {
        int idx = base + j * 256 + t;
        if (idx < M) s += deg[idx];
    }
    sh[t] = s; __syncthreads();
    for (int off = 128; off > 0; off >>= 1) {
        if (t < off) sh[t] += sh[t + off];
        __syncthreads();
    }
    if (t == 0) bsum[blockIdx.x] = sh[0];
}

// ---- scan pass 2: parallel exclusive scan of chunk sums (nb <= 256) ----
__global__ __launch_bounds__(256) void k_scan2(int* __restrict__ bsum, int nb,
                                               int* __restrict__ rowptr, int M, int Etot) {
    __shared__ int sh[256];
    int t = threadIdx.x;
    int v = (t < nb) ? bsum[t] : 0;
    sh[t] = v; __syncthreads();
    for (int off = 1; off < 256; off <<= 1) {
        int add = (t >= off) ? sh[t - off] : 0;
        __syncthreads();
        sh[t] += add;
        __syncthreads();
    }
    if (t < nb) bsum[t] = sh[t] - v;       // exclusive
    if (t == 0) rowptr[M] = Etot;
}

// ---- scan pass 3: intra-chunk exclusive scan -> rowptr ----
__global__ __launch_bounds__(256) void k_scan3(const int* __restrict__ deg,
                                               int* __restrict__ rowptr,
                                               const int* __restrict__ bsum, int M) {
    __shared__ int sh[256];
    int base = blockIdx.x * SCAN_CHUNK;
    int t = threadIdx.x;
    int v[4]; int s = 0;
    #pragma unroll
    for (int j = 0; j < 4; ++j) {
        int idx = base + 4 * t + j;
        v[j] = (idx < M) ? deg[idx] : 0;
        s += v[j];
    }
    sh[t] = s; __syncthreads();
    for (int off = 1; off < 256; off <<= 1) {
        int add = (t >= off) ? sh[t - off] : 0;
        __syncthreads();
        sh[t] += add;
        __syncthreads();
    }
    int run = sh[t] - s + bsum[blockIdx.x];
    #pragma unroll
    for (int j = 0; j < 4; ++j) {
        int idx = base + 4 * t + j;
        if (idx < M) { rowptr[idx] = run; run += v[j]; }
    }
}

// ---- atomic-free scatter: col[rowptr[dst] + rank[e]] = src ----
__global__ __launch_bounds__(256) void k_scatter2(
        const int* __restrict__ edge_i, const int* __restrict__ edge_t,
        const int* __restrict__ rank, const int* __restrict__ rowptr,
        int* __restrict__ col, int N, int E, int nbS) {
    const int bid = blockIdx.x;
    int rel = (bid >= nbS) ? 1 : 0;
    int b = bid - rel * nbS;
    const int* eg = rel ? edge_t : edge_i;
    const int* rk = rank + (size_t)rel * E;
    const int* rp = rowptr + (size_t)rel * N;
    int e = b * 1024 + threadIdx.x * 4;
    if (e + 3 < E) {
        int4 d4 = *reinterpret_cast<const int4*>(eg + E + e);
        int4 s4 = *reinterpret_cast<const int4*>(eg + e);
        int4 r4 = *reinterpret_cast<const int4*>(rk + e);
        __builtin_nontemporal_store(s4.x, &col[rp[d4.x] + r4.x]);
        __builtin_nontemporal_store(s4.y, &col[rp[d4.y] + r4.y]);
        __builtin_nontemporal_store(s4.z, &col[rp[d4.z] + r4.z]);
        __builtin_nontemporal_store(s4.w, &col[rp[d4.w] + r4.w]);
    } else {
        for (int j = 0; j < 4; ++j) {
            int ee = e + j;
            if (ee < E) col[rp[eg[E + ee]] + rk[ee]] = eg[ee];
        }
    }
}

// ---- gather-mean: 16 lanes per node, bf16 rows (256 B), both relations ----
__global__ __launch_bounds__(256) void k_gather_mean(
        const ushort* __restrict__ xib, const ushort* __restrict__ xtb,
        const int* __restrict__ rowptr, const int* __restrict__ col,
        ushort* __restrict__ mi, ushort* __restrict__ mt, int N) {
    int t = blockIdx.x * 256 + threadIdx.x;
    int node = t >> 4, lane = t & 15;
    if (node >= N) return;
    int rel = blockIdx.y;
    const ushort* xs = rel ? xtb : xib;
    ushort* mean = rel ? mt : mi;
    int rb = rel * N + node;
    int beg = rowptr[rb], end = rowptr[rb + 1];
    float a0 = 0.f, a1 = 0.f, a2 = 0.f, a3 = 0.f,
          a4 = 0.f, a5 = 0.f, a6 = 0.f, a7 = 0.f;
    int j = beg;
    for (; j + 1 < end; j += 2) {
        int s0 = col[j], s1 = col[j + 1];
        u16x8 v0 = *reinterpret_cast<const u16x8*>(xs + (size_t)s0 * 128 + lane * 8);
        u16x8 v1 = *reinterpret_cast<const u16x8*>(xs + (size_t)s1 * 128 + lane * 8);
        a0 += b2f(v0[0]) + b2f(v1[0]);  a1 += b2f(v0[1]) + b2f(v1[1]);
        a2 += b2f(v0[2]) + b2f(v1[2]);  a3 += b2f(v0[3]) + b2f(v1[3]);
        a4 += b2f(v0[4]) + b2f(v1[4]);  a5 += b2f(v0[5]) + b2f(v1[5]);
        a6 += b2f(v0[6]) + b2f(v1[6]);  a7 += b2f(v0[7]) + b2f(v1[7]);
    }
    if (j < end) {
        int s0 = col[j];
        u16x8 v0 = *reinterpret_cast<const u16x8*>(xs + (size_t)s0 * 128 + lane * 8);
        a0 += b2f(v0[0]); a1 += b2f(v0[1]); a2 += b2f(v0[2]); a3 += b2f(v0[3]);
        a4 += b2f(v0[4]); a5 += b2f(v0[5]); a6 += b2f(v0[6]); a7 += b2f(v0[7]);
    }
    float r = (end > beg) ? 1.0f / (float)(end - beg) : 0.0f;
    u16x8 o;
    o[0] = f2b(a0 * r); o[1] = f2b(a1 * r); o[2] = f2b(a2 * r); o[3] = f2b(a3 * r);
    o[4] = f2b(a4 * r); o[5] = f2b(a5 * r); o[6] = f2b(a6 * r); o[7] = f2b(a7 * r);
    *reinterpret_cast<u16x8*>(mean + (size_t)node * 128 + lane * 8) = o;
}

// ---- out = relu( [mi|mt|u](bf16, K=384) @ Bpack + bsum ) : MFMA ----
__global__ __launch_bounds__(256) void k_final_mfma(
        const ushort* __restrict__ mi, const ushort* __restrict__ mt,
        const ushort* __restrict__ ub, const ushort* __restrict__ Bp,
        const float* __restrict__ bsum, float* __restrict__ out, int N) {
    const int tid = threadIdx.x;
    const int wid = tid >> 6, lane = tid & 63;
    const int rowA = blockIdx.x * 64 + wid * 16 + (lane & 15);
    const int rA = min(rowA, N - 1);
    const int kh = (lane >> 4) * 8;
    f32x4 acc[8] = {};
    #pragma unroll
    for (int ks = 0; ks < 12; ++ks) {
        const ushort* s = (ks < 4) ? mi : (ks < 8) ? mt : ub;
        bf16x8 a = *reinterpret_cast<const bf16x8*>(s + (size_t)rA * 128 + (ks & 3) * 32 + kh);
        #pragma unroll
        for (int cf = 0; cf < 8; ++cf) {
            bf16x8 bb = *reinterpret_cast<const bf16x8*>(Bp + ((ks * 8 + cf) * 64 + lane) * 8);
            acc[cf] = __builtin_amdgcn_mfma_f32_16x16x32_bf16(a, bb, acc[cf], 0, 0, 0);
        }
    }
    const int col0 = lane & 15;
    const int rbase = blockIdx.x * 64 + wid * 16 + (lane >> 4) * 4;
    #pragma unroll
    for (int cf = 0; cf < 8; ++cf) {
        int col = cf * 16 + col0;
        float bv = bsum[col];
        #pragma unroll
        for (int r = 0; r < 4; ++r) {
            int row = rbase + r;
            if (row < N) out[(size_t)row * 128 + col] = fmaxf(acc[cf][r] + bv, 0.f);
        }
    }
}

extern "C" void kernel_launch(void* const* d_in, const int* in_sizes, int n_in,
                              void* d_out, int out_size, void* d_ws, size_t ws_size,
                              hipStream_t stream) {
    const float* x_user  = (const float*)d_in[0];
    const float* x_image = (const float*)d_in[1];
    const float* x_text  = (const float*)d_in[2];
    const int*   edge_i  = (const int*)d_in[3];
    const int*   edge_t  = (const int*)d_in[4];
    const float* W_user  = (const float*)d_in[5];
    const float* b_user  = (const float*)d_in[6];
    const float* Wl_img  = (const float*)d_in[7];
    const float* bl_img  = (const float*)d_in[8];
    const float* Wr_img  = (const float*)d_in[9];
    const float* Wl_txt  = (const float*)d_in[10];
    const float* bl_txt  = (const float*)d_in[11];
    const float* Wr_txt  = (const float*)d_in[12];

    const int N = in_sizes[0] / 256;   // 100000 nodes per type
    const int E = in_sizes[3] / 2;     // 800000 edges per relation
    const int M = 2 * N;
    const int NB = (M + SCAN_CHUNK - 1) / SCAN_CHUNK;   // <= 256

    ushort* xib  = (ushort*)d_ws;                  // N*128
    ushort* xtb  = xib + (size_t)N * 128;          // N*128
    ushort* ub   = xtb + (size_t)N * 128;          // N*128
    ushort* mi   = ub  + (size_t)N * 128;          // N*128
    ushort* mt   = mi  + (size_t)N * 128;          // N*128
    ushort* Bpu  = mt  + (size_t)N * 128;          // 32768
    ushort* Bpf  = Bpu + 32768;                    // 49152
    float*  bsum = (float*)(Bpf + 49152);          // 128
    int*    deg    = (int*)(bsum + 128);           // M
    int*    rowptr = deg + M;                      // M+1
    int*    bscan  = rowptr + (M + 1);             // NB
    int*    rank   = bscan + ((NB + 31) & ~31);    // 2E
    int*    col    = rank + (size_t)2 * E;         // 2E

    k_pack<<<(81920 + 255) / 256, 256, 0, stream>>>(
        W_user, Wl_img, Wl_txt, Wr_img, Wr_txt, bl_img, bl_txt, Bpu, Bpf, bsum);

    hipMemsetAsync(deg, 0, (size_t)M * sizeof(int), stream);

    const int nbH = (E + 1023) / 1024;             // hist blocks per relation
    const int nbU = (N + 63) / 64;                 // user-mfma blocks
    const int nbC = (2 * N * 16 + 255) / 256;      // convert blocks
    k_front<<<2 * nbH + nbU + nbC, 256, 0, stream>>>(
        x_user, x_image, x_text, edge_i, edge_t, Bpu, b_user,
        xib, xtb, ub, deg, rank, N, E, nbH, nbU);

    k_scan1<<<NB, 256, 0, stream>>>(deg, bscan, M);
    k_scan2<<<1, 256, 0, stream>>>(bscan, NB, rowptr, M, 2 * E);
    k_scan3<<<NB, 256, 0, stream>>>(deg, rowptr, bscan, M);

    const int nbS = (E + 1023) / 1024;
    k_scatter2<<<2 * nbS, 256, 0, stream>>>(edge_i, edge_t, rank, rowptr, col, N, E, nbS);

    {
        dim3 g((N * 16 + 255) / 256, 2);
        k_gather_mean<<<g, 256, 0, stream>>>(xib, xtb, rowptr, col, mi, mt, N);
    }

    k_final_mfma<<<(N + 63) / 64, 256, 0, stream>>>(
        mi, mt, ub, Bpf, bsum, (float*)d_out, N);
}

// Round 6
// 288.010 us; speedup vs baseline: 11.5494x; 1.0236x over previous
//
#include <hip/hip_runtime.h>

// ---------------------------------------------------------------------------
// HeteroGNN, round 6: algebraic collapse + back-end fusion.
//   out = relu( [mean_i | mean_t | x_user] @ [Wl_i; Wl_t; W_user@(Wr_i+Wr_t)]
//               + (b_user@(Wr_i+Wr_t) + bl_i + bl_t) )        [MFMA, K=512]
// CSR: hist w/ rank-capture (atomic-free scatter). k_back fuses gather-mean
// (into swizzled LDS) + K=512 MFMA + bias + relu.
// MFMA 16x16x32_bf16: A row=lane&15, k=(lane>>4)*8+j; B col=lane&15;
// D col=lane&15, row=(lane>>4)*4+reg  [m89-verified].
// LDS tile: [rel][64][128] bf16, 16B-chunk swizzle chunk^=(row&7) -> <=2-way.
// ---------------------------------------------------------------------------

#define SCAN_CHUNK 1024

typedef __attribute__((ext_vector_type(8))) short bf16x8;
typedef __attribute__((ext_vector_type(8))) unsigned short u16x8;
typedef __attribute__((ext_vector_type(4))) float f32x4;

__device__ __forceinline__ ushort f2b(float x) {
    union { float f; unsigned u; } v; v.f = x;
    unsigned r = (v.u + 0x7FFF + ((v.u >> 16) & 1)) >> 16;   // RNE
    return (ushort)r;
}
__device__ __forceinline__ float b2f(ushort u) {
    union { unsigned u; float f; } v; v.u = (unsigned)u << 16;
    return v.f;
}

// ---- W_comb = W_user @ (Wr_i+Wr_t)  [256x128]; bias_comb = b_user@Wr_s+bl_i+bl_t ----
__global__ __launch_bounds__(256) void k_pack_w(
        const float* __restrict__ W_user, const float* __restrict__ b_user,
        const float* __restrict__ Wr_i, const float* __restrict__ Wr_t,
        const float* __restrict__ bl_i, const float* __restrict__ bl_t,
        float* __restrict__ Wcomb, float* __restrict__ bias_comb) {
    int i = blockIdx.x * 256 + threadIdx.x;      // 32768 threads
    int k = i >> 7, c = i & 127;
    float s = 0.f;
    for (int c1 = 0; c1 < 128; ++c1)
        s += W_user[k * 128 + c1] * (Wr_i[c1 * 128 + c] + Wr_t[c1 * 128 + c]);
    Wcomb[i] = s;
    if (i < 128) {
        float b = bl_i[i] + bl_t[i];
        for (int k2 = 0; k2 < 128; ++k2)
            b += b_user[k2] * (Wr_i[k2 * 128 + i] + Wr_t[k2 * 128 + i]);
        bias_comb[i] = b;
    }
}

// ---- fragment-pack Bp [K=512 x 128]: rows 0-127 Wl_i, 128-255 Wl_t, 256-511 Wcomb ----
__global__ __launch_bounds__(256) void k_pack(
        const float* __restrict__ Wl_i, const float* __restrict__ Wl_t,
        const float* __restrict__ Wcomb, ushort* __restrict__ Bp) {
    int i = blockIdx.x * 256 + threadIdx.x;      // 65536 threads
    int j = i & 7, lane = (i >> 3) & 63, cf = (i >> 9) & 7, ks = i >> 12;
    int kk = ks * 32 + (lane >> 4) * 8 + j;
    int col = cf * 16 + (lane & 15);
    float v;
    if (kk < 128)      v = Wl_i[kk * 128 + col];
    else if (kk < 256) v = Wl_t[(kk - 128) * 128 + col];
    else               v = Wcomb[(kk - 256) * 128 + col];
    Bp[i] = f2b(v);
}

// ---- fused front: [hist+rank | bf16 convert] by block range ----
__global__ __launch_bounds__(256) void k_front(
        const float* __restrict__ x_image, const float* __restrict__ x_text,
        const int* __restrict__ edge_i, const int* __restrict__ edge_t,
        ushort* __restrict__ xib, ushort* __restrict__ xtb,
        int* __restrict__ deg, int* __restrict__ rank,
        int N, int E, int nbH) {
    const int bid = blockIdx.x;
    const int tid = threadIdx.x;

    if (bid < 2 * nbH) {
        // ---- histogram + rank capture (4 edges/thread) ----
        int rel = (bid >= nbH) ? 1 : 0;
        int b = bid - rel * nbH;
        const int* eg = rel ? edge_t : edge_i;
        int* rk = rank + (size_t)rel * E;
        int* dg = deg + (size_t)rel * N;
        int e = b * 1024 + tid * 4;
        if (e + 3 < E) {
            int4 d4 = *reinterpret_cast<const int4*>(eg + E + e);
            int4 r4;
            r4.x = atomicAdd(&dg[d4.x], 1);
            r4.y = atomicAdd(&dg[d4.y], 1);
            r4.z = atomicAdd(&dg[d4.z], 1);
            r4.w = atomicAdd(&dg[d4.w], 1);
            *reinterpret_cast<int4*>(rk + e) = r4;
        } else {
            for (int j = 0; j < 4; ++j) {
                int ee = e + j;
                if (ee < E) rk[ee] = atomicAdd(&dg[eg[E + ee]], 1);
            }
        }
    } else {
        // ---- x_image/x_text f32 -> bf16 ----
        int t = (bid - 2 * nbH) * 256 + tid;
        int n8 = N * 16;
        if (t >= 2 * n8) return;
        const float* src = (t < n8) ? x_image : x_text;
        ushort* dst = (t < n8) ? xib : xtb;
        int i = (t < n8) ? t : t - n8;
        float4 f0 = *reinterpret_cast<const float4*>(src + (size_t)i * 8);
        float4 f1 = *reinterpret_cast<const float4*>(src + (size_t)i * 8 + 4);
        u16x8 o;
        o[0] = f2b(f0.x); o[1] = f2b(f0.y); o[2] = f2b(f0.z); o[3] = f2b(f0.w);
        o[4] = f2b(f1.x); o[5] = f2b(f1.y); o[6] = f2b(f1.z); o[7] = f2b(f1.w);
        *reinterpret_cast<u16x8*>(dst + (size_t)i * 8) = o;
    }
}

// ---- scan pass 1: per-chunk sums (over M = 2N) ----
__global__ __launch_bounds__(256) void k_scan1(const int* __restrict__ deg,
                                               int* __restrict__ bsum, int M) {
    __shared__ int sh[256];
    int base = blockIdx.x * SCAN_CHUNK;
    int t = threadIdx.x;
    int s = 0;
    #pragma unroll
    for (int j = 0; j < 4; ++j) {
        int idx = base + j * 256 + t;
        if (idx < M) s += deg[idx];
    }
    sh[t] = s; __syncthreads();
    for (int off = 128; off > 0; off >>= 1) {
        if (t < off) sh[t] += sh[t + off];
        __syncthreads();
    }
    if (t == 0) bsum[blockIdx.x] = sh[0];
}

// ---- scan pass 2: parallel exclusive scan of chunk sums (nb <= 256) ----
__global__ __launch_bounds__(256) void k_scan2(int* __restrict__ bsum, int nb,
                                               int* __restrict__ rowptr, int M, int Etot) {
    __shared__ int sh[256];
    int t = threadIdx.x;
    int v = (t < nb) ? bsum[t] : 0;
    sh[t] = v; __syncthreads();
    for (int off = 1; off < 256; off <<= 1) {
        int add = (t >= off) ? sh[t - off] : 0;
        __syncthreads();
        sh[t] += add;
        __syncthreads();
    }
    if (t < nb) bsum[t] = sh[t] - v;       // exclusive
    if (t == 0) rowptr[M] = Etot;
}

// ---- scan pass 3: intra-chunk exclusive scan -> rowptr ----
__global__ __launch_bounds__(256) void k_scan3(const int* __restrict__ deg,
                                               int* __restrict__ rowptr,
                                               const int* __restrict__ bsum, int M) {
    __shared__ int sh[256];
    int base = blockIdx.x * SCAN_CHUNK;
    int t = threadIdx.x;
    int v[4]; int s = 0;
    #pragma unroll
    for (int j = 0; j < 4; ++j) {
        int idx = base + 4 * t + j;
        v[j] = (idx < M) ? deg[idx] : 0;
        s += v[j];
    }
    sh[t] = s; __syncthreads();
    for (int off = 1; off < 256; off <<= 1) {
        int add = (t >= off) ? sh[t - off] : 0;
        __syncthreads();
        sh[t] += add;
        __syncthreads();
    }
    int run = sh[t] - s + bsum[blockIdx.x];
    #pragma unroll
    for (int j = 0; j < 4; ++j) {
        int idx = base + 4 * t + j;
        if (idx < M) { rowptr[idx] = run; run += v[j]; }
    }
}

// ---- atomic-free scatter: col[rowptr[dst] + rank[e]] = src ----
__global__ __launch_bounds__(256) void k_scatter2(
        const int* __restrict__ edge_i, const int* __restrict__ edge_t,
        const int* __restrict__ rank, const int* __restrict__ rowptr,
        int* __restrict__ col, int N, int E, int nbS) {
    const int bid = blockIdx.x;
    int rel = (bid >= nbS) ? 1 : 0;
    int b = bid - rel * nbS;
    const int* eg = rel ? edge_t : edge_i;
    const int* rk = rank + (size_t)rel * E;
    const int* rp = rowptr + (size_t)rel * N;
    int e = b * 1024 + threadIdx.x * 4;
    if (e + 3 < E) {
        int4 d4 = *reinterpret_cast<const int4*>(eg + E + e);
        int4 s4 = *reinterpret_cast<const int4*>(eg + e);
        int4 r4 = *reinterpret_cast<const int4*>(rk + e);
        __builtin_nontemporal_store(s4.x, &col[rp[d4.x] + r4.x]);
        __builtin_nontemporal_store(s4.y, &col[rp[d4.y] + r4.y]);
        __builtin_nontemporal_store(s4.z, &col[rp[d4.z] + r4.z]);
        __builtin_nontemporal_store(s4.w, &col[rp[d4.w] + r4.w]);
    } else {
        for (int j = 0; j < 4; ++j) {
            int ee = e + j;
            if (ee < E) col[rp[eg[E + ee]] + rk[ee]] = eg[ee];
        }
    }
}

// ---- fused back: gather means into swizzled LDS + K=512 MFMA + bias + relu ----
__global__ __launch_bounds__(256) void k_back(
        const float* __restrict__ x_user,
        const ushort* __restrict__ xib, const ushort* __restrict__ xtb,
        const int* __restrict__ rowptr, const int* __restrict__ col,
        const ushort* __restrict__ Bp, const float* __restrict__ bias,
        float* __restrict__ out, int N) {
    __shared__ ushort lds[2][64][128];   // [rel][node][col], 16B-chunk swizzled
    const int tid = threadIdx.x;
    const int base = blockIdx.x * 64;

    // ======== gather phase: 4 lanes per node, 32 cols each ========
    {
        const int node = tid >> 2;       // 0..63
        const int sub = tid & 3;         // col block [sub*32, sub*32+32)
        const int gnode = base + node;
        for (int rel = 0; rel < 2; ++rel) {
            const ushort* xs = rel ? xtb : xib;
            float a[32];
            #pragma unroll
            for (int q = 0; q < 32; ++q) a[q] = 0.f;
            int beg = 0, end = 0;
            if (gnode < N) {
                int rb = rel * N + gnode;
                beg = rowptr[rb]; end = rowptr[rb + 1];
            }
            int j = beg;
            for (; j + 1 < end; j += 2) {
                int s0 = col[j], s1 = col[j + 1];
                const ushort* r0 = xs + (size_t)s0 * 128 + sub * 32;
                const ushort* r1 = xs + (size_t)s1 * 128 + sub * 32;
                #pragma unroll
                for (int q = 0; q < 4; ++q) {
                    u16x8 v0 = *reinterpret_cast<const u16x8*>(r0 + q * 8);
                    u16x8 v1 = *reinterpret_cast<const u16x8*>(r1 + q * 8);
                    #pragma unroll
                    for (int e2 = 0; e2 < 8; ++e2)
                        a[q * 8 + e2] += b2f(v0[e2]) + b2f(v1[e2]);
                }
            }
            if (j < end) {
                int s0 = col[j];
                const ushort* r0 = xs + (size_t)s0 * 128 + sub * 32;
                #pragma unroll
                for (int q = 0; q < 4; ++q) {
                    u16x8 v0 = *reinterpret_cast<const u16x8*>(r0 + q * 8);
                    #pragma unroll
                    for (int e2 = 0; e2 < 8; ++e2)
                        a[q * 8 + e2] += b2f(v0[e2]);
                }
            }
            float r = (end > beg) ? 1.0f / (float)(end - beg) : 0.0f;
            #pragma unroll
            for (int q = 0; q < 4; ++q) {
                u16x8 o;
                #pragma unroll
                for (int e2 = 0; e2 < 8; ++e2) o[e2] = f2b(a[q * 8 + e2] * r);
                int chunk = (sub * 4 + q) ^ (node & 7);          // 16B-chunk swizzle
                *reinterpret_cast<u16x8*>(&lds[rel][node][chunk * 8]) = o;
            }
        }
    }
    __syncthreads();

    // ======== MFMA phase: K=512 = [mi(128) | mt(128) | x_user(256)] ========
    const int wid = tid >> 6, lane = tid & 63;
    const int lrow = lane & 15;
    const int row16 = wid * 16 + lrow;           // LDS row / node within block
    const int qh = lane >> 4;                    // k-quarter 0..3
    f32x4 acc[8] = {};

    #pragma unroll
    for (int ks = 0; ks < 8; ++ks) {             // means from LDS
        int rel = ks >> 2;
        int chunk = ((ks & 3) * 4 + qh) ^ (row16 & 7);
        bf16x8 aa = *reinterpret_cast<const bf16x8*>(&lds[rel][row16][chunk * 8]);
        #pragma unroll
        for (int cf = 0; cf < 8; ++cf) {
            bf16x8 bb = *reinterpret_cast<const bf16x8*>(Bp + ((ks * 8 + cf) * 64 + lane) * 8);
            acc[cf] = __builtin_amdgcn_mfma_f32_16x16x32_bf16(aa, bb, acc[cf], 0, 0, 0);
        }
    }

    const int grow = min(base + row16, N - 1);
    const float* Xr = x_user + (size_t)grow * 256;
    #pragma unroll
    for (int ks = 8; ks < 16; ++ks) {            // x_user direct, inline cvt
        int k0 = (ks - 8) * 32 + qh * 8;
        float4 f0 = *reinterpret_cast<const float4*>(Xr + k0);
        float4 f1 = *reinterpret_cast<const float4*>(Xr + k0 + 4);
        bf16x8 aa;
        aa[0] = (short)f2b(f0.x); aa[1] = (short)f2b(f0.y);
        aa[2] = (short)f2b(f0.z); aa[3] = (short)f2b(f0.w);
        aa[4] = (short)f2b(f1.x); aa[5] = (short)f2b(f1.y);
        aa[6] = (short)f2b(f1.z); aa[7] = (short)f2b(f1.w);
        #pragma unroll
        for (int cf = 0; cf < 8; ++cf) {
            bf16x8 bb = *reinterpret_cast<const bf16x8*>(Bp + ((ks * 8 + cf) * 64 + lane) * 8);
            acc[cf] = __builtin_amdgcn_mfma_f32_16x16x32_bf16(aa, bb, acc[cf], 0, 0, 0);
        }
    }

    // ======== epilogue: bias + relu + store ========
    const int col0 = lane & 15;
    const int rbase = base + wid * 16 + qh * 4;
    #pragma unroll
    for (int cf = 0; cf < 8; ++cf) {
        int c = cf * 16 + col0;
        float bv = bias[c];
        #pragma unroll
        for (int r = 0; r < 4; ++r) {
            int row = rbase + r;
            if (row < N) out[(size_t)row * 128 + c] = fmaxf(acc[cf][r] + bv, 0.f);
        }
    }
}

extern "C" void kernel_launch(void* const* d_in, const int* in_sizes, int n_in,
                              void* d_out, int out_size, void* d_ws, size_t ws_size,
                              hipStream_t stream) {
    const float* x_user  = (const float*)d_in[0];
    const float* x_image = (const float*)d_in[1];
    const float* x_text  = (const float*)d_in[2];
    const int*   edge_i  = (const int*)d_in[3];
    const int*   edge_t  = (const int*)d_in[4];
    const float* W_user  = (const float*)d_in[5];
    const float* b_user  = (const float*)d_in[6];
    const float* Wl_img  = (const float*)d_in[7];
    const float* bl_img  = (const float*)d_in[8];
    const float* Wr_img  = (const float*)d_in[9];
    const float* Wl_txt  = (const float*)d_in[10];
    const float* bl_txt  = (const float*)d_in[11];
    const float* Wr_txt  = (const float*)d_in[12];

    const int N = in_sizes[0] / 256;   // 100000 nodes per type
    const int E = in_sizes[3] / 2;     // 800000 edges per relation
    const int M = 2 * N;
    const int NB = (M + SCAN_CHUNK - 1) / SCAN_CHUNK;   // <= 256

    ushort* xib    = (ushort*)d_ws;                // N*128
    ushort* xtb    = xib + (size_t)N * 128;        // N*128
    ushort* Bp     = xtb + (size_t)N * 128;        // 65536
    float*  Wcomb  = (float*)(Bp + 65536);         // 32768
    float*  bias   = Wcomb + 32768;                // 128
    int*    deg    = (int*)(bias + 128);           // M
    int*    rowptr = deg + M;                      // M+1 (padded to M+4)
    int*    bscan  = rowptr + (M + 4);             // NB (<=256)
    int*    rank   = bscan + 256;                  // 2E
    int*    col    = rank + (size_t)2 * E;         // 2E

    k_pack_w<<<128, 256, 0, stream>>>(W_user, b_user, Wr_img, Wr_txt,
                                      bl_img, bl_txt, Wcomb, bias);
    k_pack<<<256, 256, 0, stream>>>(Wl_img, Wl_txt, Wcomb, Bp);

    hipMemsetAsync(deg, 0, (size_t)M * sizeof(int), stream);

    const int nbH = (E + 1023) / 1024;             // hist blocks per relation
    const int nbC = (2 * N * 16 + 255) / 256;      // convert blocks
    k_front<<<2 * nbH + nbC, 256, 0, stream>>>(
        x_image, x_text, edge_i, edge_t, xib, xtb, deg, rank, N, E, nbH);

    k_scan1<<<NB, 256, 0, stream>>>(deg, bscan, M);
    k_scan2<<<1, 256, 0, stream>>>(bscan, NB, rowptr, M, 2 * E);
    k_scan3<<<NB, 256, 0, stream>>>(deg, rowptr, bscan, M);

    const int nbS = (E + 1023) / 1024;
    k_scatter2<<<2 * nbS, 256, 0, stream>>>(edge_i, edge_t, rank, rowptr, col, N, E, nbS);

    k_back<<<(N + 63) / 64, 256, 0, stream>>>(
        x_user, xib, xtb, rowptr, col, Bp, bias, (float*)d_out, N);
}